// Round 1
// baseline (177.415 us; speedup 1.0000x reference)
//
#include <hip/hip_runtime.h>

#define HIDDEN 512
#define HEADS 8
#define DK 64
#define B_ 4
#define S_ 1024
#define NEGV -1000000000.0f

typedef _Float16 half8 __attribute__((ext_vector_type(8)));
typedef _Float16 half4 __attribute__((ext_vector_type(4)));
typedef float f32x4 __attribute__((ext_vector_type(4)));

// ---------------- fp32 -> fp16 converters ----------------
__global__ __launch_bounds__(256) void cvt3(const float* __restrict__ a0,
                                            const float* __restrict__ a1,
                                            const float* __restrict__ a2,
                                            _Float16* o0, _Float16* o1, _Float16* o2) {
  const float* src = blockIdx.y == 0 ? a0 : (blockIdx.y == 1 ? a1 : a2);
  _Float16* dst = blockIdx.y == 0 ? o0 : (blockIdx.y == 1 ? o1 : o2);
  int i = (blockIdx.x * 256 + threadIdx.x) * 4;
  float4 v = *(const float4*)(src + i);
  half4 h = {(_Float16)v.x, (_Float16)v.y, (_Float16)v.z, (_Float16)v.w};
  *(half4*)(dst + i) = h;
}

__global__ __launch_bounds__(256) void cvt4(const float* __restrict__ a0,
                                            const float* __restrict__ a1,
                                            const float* __restrict__ a2,
                                            const float* __restrict__ a3,
                                            _Float16* o0, _Float16* o1, _Float16* o2, _Float16* o3) {
  const float* src = blockIdx.y == 0 ? a0 : (blockIdx.y == 1 ? a1 : (blockIdx.y == 2 ? a2 : a3));
  _Float16* dst = blockIdx.y == 0 ? o0 : (blockIdx.y == 1 ? o1 : (blockIdx.y == 2 ? o2 : o3));
  int i = (blockIdx.x * 256 + threadIdx.x) * 4;
  float4 v = *(const float4*)(src + i);
  half4 h = {(_Float16)v.x, (_Float16)v.y, (_Float16)v.z, (_Float16)v.w};
  *(half4*)(dst + i) = h;
}

// ---------------- fused QKV projection ----------------
// C-tile 64x64, 4 waves, each wave does 16 rows x 64 cols.
// n-block 0..7 -> Q (scaled), 8..15 -> K, 16..23 -> V (transposed output).
__global__ __launch_bounds__(256) void proj_qkv(
    const _Float16* __restrict__ q16, const _Float16* __restrict__ k16,
    const _Float16* __restrict__ v16,
    const _Float16* __restrict__ wq, const _Float16* __restrict__ wk,
    const _Float16* __restrict__ wv,
    const float* __restrict__ bq, const float* __restrict__ bk,
    const float* __restrict__ bv,
    _Float16* __restrict__ qh, _Float16* __restrict__ kh, _Float16* __restrict__ vt) {
  int m0 = blockIdx.x * 64;
  int nb = blockIdx.y;
  int which = nb >> 3;
  int n0 = (nb & 7) * 64;
  const _Float16* X = which == 0 ? q16 : (which == 1 ? k16 : v16);
  const _Float16* W = which == 0 ? wq : (which == 1 ? wk : wv);
  const float* bias = which == 0 ? bq : (which == 1 ? bk : bv);

  int tid = threadIdx.x;
  int wave = tid >> 6, lane = tid & 63;
  int r16 = lane & 15, quad = lane >> 4;

  const _Float16* Xp = X + (m0 + wave * 16 + r16) * HIDDEN + quad * 8;
  const _Float16* Wp = W + (n0 + r16) * HIDDEN + quad * 8;

  f32x4 acc[4] = {};
  for (int k0 = 0; k0 < HIDDEN; k0 += 32) {
    half8 a = *(const half8*)(Xp + k0);
#pragma unroll
    for (int nt = 0; nt < 4; nt++) {
      half8 bfr = *(const half8*)(Wp + nt * 16 * HIDDEN + k0);
      acc[nt] = __builtin_amdgcn_mfma_f32_16x16x32_f16(a, bfr, acc[nt], 0, 0, 0);
    }
  }

  __shared__ _Float16 T[64][72];

  if (which < 2) {
    _Float16* OUT = which == 0 ? qh : kh;
    float scale = which == 0 ? 0.125f : 1.0f;  // DK^-0.5 = 1/8
#pragma unroll
    for (int nt = 0; nt < 4; nt++) {
      int gcol = n0 + nt * 16 + r16;
      float bv_ = bias[gcol];
      int h = gcol >> 6, d = gcol & 63;
#pragma unroll
      for (int r = 0; r < 4; r++) {
        int grow = m0 + wave * 16 + quad * 4 + r;
        int bb = grow >> 10, s = grow & 1023;
        float val = (acc[nt][r] + bv_) * scale;
        OUT[((bb * HEADS + h) * S_ + s) * DK + d] = (_Float16)val;
      }
    }
  } else {
    // V: transpose 64x64 tile via LDS, write vt[b][h][d][s]
#pragma unroll
    for (int nt = 0; nt < 4; nt++) {
      int lc = nt * 16 + r16;
      float bv_ = bias[n0 + lc];
#pragma unroll
      for (int r = 0; r < 4; r++) {
        int lr = wave * 16 + quad * 4 + r;
        T[lr][lc] = (_Float16)(acc[nt][r] + bv_);
      }
    }
    __syncthreads();
    int dl = tid >> 2;        // 0..63 : local d
    int s4 = (tid & 3) * 16;  // 0,16,32,48 : local s quad
    _Float16 tmp[16];
#pragma unroll
    for (int i = 0; i < 16; i++) tmp[i] = T[s4 + i][dl];
    int h = n0 >> 6;
    int bb = m0 >> 10;
    int s0 = m0 & 1023;
    _Float16* p = vt + ((bb * HEADS + h) * DK + dl) * S_ + s0 + s4;
    *(half8*)(p) = *(half8*)(tmp);
    *(half8*)(p + 8) = *(half8*)(tmp + 8);
  }
}

// ---------------- attention ----------------
// grid (S/64, B*H); 4 waves/block, each wave owns 16 q-rows; flash-style.
__global__ __launch_bounds__(256) void attn_kernel(
    const _Float16* __restrict__ qh, const _Float16* __restrict__ kh,
    const _Float16* __restrict__ vt,
    const float* __restrict__ attn_bias, const int* __restrict__ gmask,
    const float* __restrict__ subsq, _Float16* __restrict__ ao) {
  int bh = blockIdx.y;
  int b = bh >> 3, h = bh & 7;
  int tid = threadIdx.x;
  int wave = tid >> 6, lane = tid & 63;
  int col = lane & 15, quad = lane >> 4;
  int q0 = blockIdx.x * 64 + wave * 16;

  const _Float16* Q = qh + (bh * S_ + q0) * DK;
  const _Float16* K = kh + bh * S_ * DK;
  const _Float16* V = vt + bh * DK * S_;
  const float* BI = attn_bias + (size_t)(bh * S_ + q0) * S_;
  const int* GM = gmask + (size_t)(b * S_ + q0) * S_;
  const float* SQ = subsq + (size_t)(b * S_ + q0) * S_;

  half8 qf0 = *(const half8*)(Q + col * DK + quad * 8);
  half8 qf1 = *(const half8*)(Q + col * DK + 32 + quad * 8);

  f32x4 acc[4] = {};
  float m_r[4], l_r[4];
#pragma unroll
  for (int r = 0; r < 4; r++) {
    m_r[r] = -1e38f;
    l_r[r] = 0.0f;
  }

  __shared__ _Float16 P[4][16][32];

  for (int kc = 0; kc < S_; kc += 32) {
    // QK^T: 16x32 scores (2 tiles of 16x16), K-dim = d = 64 (2 MFMAs each)
    f32x4 s[2];
#pragma unroll
    for (int t2 = 0; t2 < 2; t2++) {
      const _Float16* Kp = K + (kc + t2 * 16 + col) * DK + quad * 8;
      half8 kf0 = *(const half8*)(Kp);
      half8 kf1 = *(const half8*)(Kp + 32);
      f32x4 z = {};
      z = __builtin_amdgcn_mfma_f32_16x16x32_f16(qf0, kf0, z, 0, 0, 0);
      z = __builtin_amdgcn_mfma_f32_16x16x32_f16(qf1, kf1, z, 0, 0, 0);
      s[t2] = z;
    }
    // bias + masks (scale already folded into qh)
    float x[2][4];
#pragma unroll
    for (int t2 = 0; t2 < 2; t2++) {
      int kk = kc + t2 * 16 + col;
#pragma unroll
      for (int r = 0; r < 4; r++) {
        int qr = quad * 4 + r;
        int gm = GM[qr * S_ + kk];
        float xv = s[t2][r] + BI[qr * S_ + kk] + SQ[qr * S_ + kk];
        x[t2][r] = (gm == 0) ? NEGV : xv;
      }
    }
    // online softmax (row lives across the 16 lanes of this quad)
#pragma unroll
    for (int r = 0; r < 4; r++) {
      float mx = fmaxf(x[0][r], x[1][r]);
#pragma unroll
      for (int mm = 1; mm < 16; mm <<= 1) mx = fmaxf(mx, __shfl_xor(mx, mm));
      float mnew = fmaxf(m_r[r], mx);
      float f = __expf(m_r[r] - mnew);
      float p0 = __expf(x[0][r] - mnew);
      float p1 = __expf(x[1][r] - mnew);
      float ps = p0 + p1;
#pragma unroll
      for (int mm = 1; mm < 16; mm <<= 1) ps += __shfl_xor(ps, mm);
      l_r[r] = l_r[r] * f + ps;
      m_r[r] = mnew;
#pragma unroll
      for (int nt = 0; nt < 4; nt++) acc[nt][r] *= f;
      // store P tile with per-quad column rotation (bank-conflict-free, 16B-readable)
      int row = quad * 4 + r;
      P[wave][row][(col + quad * 8) & 31] = (_Float16)p0;
      P[wave][row][(16 + col + quad * 8) & 31] = (_Float16)p1;
    }
    __syncthreads();
    // P as A-fragment: lane reads row (lane&15), logical cols quad*8..+7
    int blk = (quad + (col >> 2)) & 3;
    half8 pf = *(const half8*)(&P[wave][col][blk * 8]);
#pragma unroll
    for (int nt = 0; nt < 4; nt++) {
      half8 vf = *(const half8*)(V + (nt * 16 + col) * S_ + kc + quad * 8);
      acc[nt] = __builtin_amdgcn_mfma_f32_16x16x32_f16(pf, vf, acc[nt], 0, 0, 0);
    }
    __syncthreads();
  }

  // epilogue: normalize, write attention out [b][s][h*64+d] fp16
#pragma unroll
  for (int nt = 0; nt < 4; nt++) {
#pragma unroll
    for (int r = 0; r < 4; r++) {
      int qr = q0 + quad * 4 + r;
      float val = acc[nt][r] / l_r[r];
      ao[(b * S_ + qr) * HIDDEN + h * DK + nt * 16 + col] = (_Float16)val;
    }
  }
}

// ---------------- output projection ----------------
__global__ __launch_bounds__(256) void out_proj(
    const _Float16* __restrict__ ao, const _Float16* __restrict__ wo,
    const float* __restrict__ bo, float* __restrict__ out) {
  int m0 = blockIdx.x * 64;
  int n0 = blockIdx.y * 64;
  int tid = threadIdx.x, wave = tid >> 6, lane = tid & 63;
  int r16 = lane & 15, quad = lane >> 4;
  const _Float16* Ap = ao + (m0 + wave * 16 + r16) * HIDDEN + quad * 8;
  const _Float16* Wp = wo + (n0 + r16) * HIDDEN + quad * 8;
  f32x4 acc[4] = {};
  for (int k0 = 0; k0 < HIDDEN; k0 += 32) {
    half8 a = *(const half8*)(Ap + k0);
#pragma unroll
    for (int nt = 0; nt < 4; nt++) {
      half8 bfr = *(const half8*)(Wp + nt * 16 * HIDDEN + k0);
      acc[nt] = __builtin_amdgcn_mfma_f32_16x16x32_f16(a, bfr, acc[nt], 0, 0, 0);
    }
  }
#pragma unroll
  for (int nt = 0; nt < 4; nt++) {
    int gcol = n0 + nt * 16 + r16;
    float bv_ = bo[gcol];
#pragma unroll
    for (int r = 0; r < 4; r++) {
      int grow = m0 + wave * 16 + quad * 4 + r;
      out[grow * HIDDEN + gcol] = acc[nt][r] + bv_;
    }
  }
}

// ---------------- launch ----------------
extern "C" void kernel_launch(void* const* d_in, const int* in_sizes, int n_in,
                              void* d_out, int out_size, void* d_ws, size_t ws_size,
                              hipStream_t stream) {
  const float* q = (const float*)d_in[0];
  const float* k = (const float*)d_in[1];
  const float* v = (const float*)d_in[2];
  const float* attn_bias = (const float*)d_in[3];
  const int* gmask = (const int*)d_in[4];
  const float* subsq = (const float*)d_in[5];
  const float* Wq = (const float*)d_in[6];
  const float* bq = (const float*)d_in[7];
  const float* Wk = (const float*)d_in[8];
  const float* bk = (const float*)d_in[9];
  const float* Wv = (const float*)d_in[10];
  const float* bv = (const float*)d_in[11];
  const float* Wo = (const float*)d_in[12];
  const float* bo = (const float*)d_in[13];

  char* ws = (char*)d_ws;
  _Float16* q16 = (_Float16*)(ws + 0);
  _Float16* k16 = (_Float16*)(ws + 4194304);
  _Float16* v16 = (_Float16*)(ws + 8388608);
  _Float16* wq16 = (_Float16*)(ws + 12582912);
  _Float16* wk16 = (_Float16*)(ws + 13107200);
  _Float16* wv16 = (_Float16*)(ws + 13631488);
  _Float16* wo16 = (_Float16*)(ws + 14155776);
  _Float16* qhb = (_Float16*)(ws + 14680064);
  _Float16* khb = (_Float16*)(ws + 18874368);
  _Float16* vtb = (_Float16*)(ws + 23068672);
  _Float16* aob = (_Float16*)(ws + 27262976);

  cvt3<<<dim3(2048, 3), 256, 0, stream>>>(q, k, v, q16, k16, v16);
  cvt4<<<dim3(256, 4), 256, 0, stream>>>(Wq, Wk, Wv, Wo, wq16, wk16, wv16, wo16);
  proj_qkv<<<dim3(64, 24), 256, 0, stream>>>(q16, k16, v16, wq16, wk16, wv16,
                                             bq, bk, bv, qhb, khb, vtb);
  attn_kernel<<<dim3(16, 32), 256, 0, stream>>>(qhb, khb, vtb, attn_bias, gmask,
                                                subsq, aob);
  out_proj<<<dim3(64, 8), 256, 0, stream>>>(aob, wo16, bo, (float*)d_out);
}